// Round 10
// baseline (231.346 us; speedup 1.0000x reference)
//
#include <hip/hip_runtime.h>
#include <math.h>

#define Hh 8
#define Ll 1024
#define KF 24
#define Dm 512
#define EPSf 1e-5f
#define LK (Ll*KF)   // 24576 rows (t,kf) per head

typedef __attribute__((ext_vector_type(8))) short sh8;
typedef __attribute__((ext_vector_type(4))) short sh4;
typedef __attribute__((ext_vector_type(4))) float f32x4;

// ---- workspace offsets (floats) ----
#define OFF_SIM    1572864
#define OFF_LOGITS 1581056
#define OFF_GATES  1589248
#define OFF_FACTOR 1597440
#define OFF_VCB    1605632     // bf16 vc
#define OFF_KCB    7897088     // bf16 kc
#define OFF_QPK    14188544    // bf16 Q A-frags
#define OFF_MPK    14450688    // bf16 M B-frags
#define OFF_WOPK   14467072    // bf16 Wo B-frags
#define OFF_CPK    14598144    // bf16 ctxt A-frags
#define OFF_CZP    26771456    // bf16 chunk partials (ushort)
#define OFF_CPART  29392896    // fp32 accumulated cpart (2 MB)
// pack overlays inside CZP region (all consumed before p3cz writes czp):
#define OFF_FPK_F  26771456    // Fpk16: 24*64*1024 ush
#define OFF_UPK_F  27607040
#define OFF_APK_F  28131328
#define OFF_BPK_F  28393472

__device__ inline unsigned short f2bf(float x){
    unsigned int u = __float_as_uint(x);
    unsigned int r = (u + 0x7fffu + ((u>>16)&1u)) >> 16;
    return (unsigned short)r;
}
__device__ inline float bf2f(unsigned short u){ return __uint_as_float(((unsigned int)u)<<16); }
__device__ inline sh8 ld8_8B(const unsigned short* p){
    union { sh8 s; sh4 h[2]; } u;
    u.h[0] = *(const sh4*)(p);
    u.h[1] = *(const sh4*)(p+4);
    return u.s;
}

// ---------- fused packing kernel ----------
// 0..63: x A-frags | 64..159: W qkv B-frags | 160..191: Wo | 192..199: M
// 200..295: Fpk16 (LDS-staged filt column) | 296: zero logits | 297..360: zero cpart
__global__ __launch_bounds__(256) void pack_all_kernel(
    const float* __restrict__ x,
    const float* __restrict__ Wq, const float* __restrict__ Wk, const float* __restrict__ Wv,
    const float* __restrict__ Wo, const float* __restrict__ kvs, const float* __restrict__ Wg,
    const float* __restrict__ filt,
    unsigned short* __restrict__ Apk, unsigned short* __restrict__ Bpk,
    unsigned short* __restrict__ Wopk, unsigned short* __restrict__ Mpk,
    unsigned short* __restrict__ Fpk16, float* __restrict__ logits,
    float* __restrict__ cpart)
{
    __shared__ float fl[1024];
    int bid = blockIdx.x, tid = threadIdx.x;
    if (bid < 64){
        int mb = bid;
        for (int ks=0; ks<16; ks++){
            #pragma unroll
            for (int p=0;p<2;p++){
                int e = tid + p*256;
                int lane = e>>3, j = e&7;
                int m = mb*16 + (lane&15);
                int k = ks*32 + ((lane>>4)&3)*8 + j;
                Apk[(mb*16+ks)*512 + e] = f2bf(x[m*Dm + k]);
            }
        }
    } else if (bid < 160){
        int nb = bid - 64;
        int n0 = nb*16;
        int mm = n0>>9;
        const float* W = (mm==0)?Wq:((mm==1)?Wk:Wv);
        int coff = n0 & 511;
        for (int ks=0; ks<16; ks++){
            #pragma unroll
            for (int p=0;p<2;p++){
                int e = tid + p*256;
                int lane = e>>3, j = e&7;
                int kk = ks*32 + ((lane>>4)&3)*8 + j;
                Bpk[(nb*16+ks)*512 + e] = f2bf(W[kk*Dm + coff + (lane&15)]);
            }
        }
    } else if (bid < 192){
        int nb = bid - 160;
        int n0 = nb*16;
        for (int ks=0; ks<16; ks++){
            #pragma unroll
            for (int p=0;p<2;p++){
                int e = tid + p*256;
                int lane = e>>3, j = e&7;
                int kk = ks*32 + ((lane>>4)&3)*8 + j;
                Wopk[(nb*16+ks)*512 + e] = f2bf(Wo[kk*Dm + n0 + (lane&15)]);
            }
        }
    } else if (bid < 200){
        int hd = bid - 192;
        for (int it=0; it<16; it++){
            int idx = tid + it*256;
            int f = idx & 511, ksnb = idx >> 9;
            int nb = ksnb>>1, ks = ksnb&1;
            int lane = f>>3, j = f&7;
            int e = nb*16 + (lane&15);
            int d = ks*32 + ((lane>>4)&3)*8 + j;
            Mpk[hd*4096 + idx] = f2bf(kvs[(hd*64+e)*64 + d]*Wg[e*64+d]);
        }
    } else if (bid < 296){
        int b2 = bid - 200;            // 24 kf x 4 groups
        int kf = b2>>2, g = b2&3;
        for (int i=tid; i<1024; i+=256) fl[i] = filt[i*KF + kf];
        __syncthreads();
        for (int ti=0; ti<16; ti++){
            int d16 = g*16 + ti;
            unsigned short* dst = Fpk16 + (kf*64 + d16)*1024;
            #pragma unroll
            for (int p2=0;p2<4;p2++){
                int e = tid + p2*256;
                int ks = e>>9, f = e&511;
                int lane = f>>3, j = f&7;
                int m = lane&15;
                int k = ks*32 + ((lane>>4)&3)*8 + j;
                int fidx = 16*d16 + m - k;
                float v = (fidx>=0) ? fl[fidx] : 0.0f;
                dst[e] = f2bf(v);
            }
        }
    } else if (bid == 296){
        for (int i=tid; i<Hh*Ll; i+=256) logits[i] = 0.f;
    } else {
        int zb = bid - 297;            // 64 blocks x 8192 floats = 512K floats
        int base = zb*8192;
        for (int i=tid; i<8192; i+=256) cpart[base+i] = 0.f;
    }
}

// ---------- fused QKV GEMM + sim + normalize + pack ----------
__global__ __launch_bounds__(64) void qkvn_kernel(
    const unsigned short* __restrict__ Apk, const unsigned short* __restrict__ Bpk,
    const float* __restrict__ bq, const float* __restrict__ bk, const float* __restrict__ bv,
    const float* __restrict__ qks, float* __restrict__ simg,
    unsigned short* __restrict__ Upk, unsigned short* __restrict__ Qpk)
{
    int mb = blockIdx.x, hd = blockIdx.y;
    int lane = threadIdx.x, quad = lane>>4, lm = lane&15;
    f32x4 acc[3][4];
    #pragma unroll
    for (int mm=0;mm<3;mm++)
        #pragma unroll
        for (int nbl=0;nbl<4;nbl++) acc[mm][nbl]=(f32x4){0.f,0.f,0.f,0.f};
    for (int ks=0; ks<16; ks++){
        sh8 a = *(const sh8*)(Apk + (mb*16+ks)*512 + lane*8);
        #pragma unroll
        for (int mm=0;mm<3;mm++)
            #pragma unroll
            for (int nbl=0;nbl<4;nbl++){
                sh8 b = *(const sh8*)(Bpk + ((mm*32 + hd*4 + nbl)*16 + ks)*512 + lane*8);
                acc[mm][nbl] = __builtin_amdgcn_mfma_f32_16x16x32_bf16(a, b, acc[mm][nbl], 0,0,0);
            }
    }
    #pragma unroll
    for (int nbl=0;nbl<4;nbl++){
        float bqv = bq[hd*64 + nbl*16 + lm];
        float bkv = bk[hd*64 + nbl*16 + lm];
        float bvv = bv[hd*64 + nbl*16 + lm];
        #pragma unroll
        for (int r=0;r<4;r++){
            acc[0][nbl][r] += bqv; acc[1][nbl][r] += bkv; acc[2][nbl][r] += bvv;
        }
    }
    float simr[4], k2r[4], v2r[4];
    #pragma unroll
    for (int r=0;r<4;r++){
        float ps=0.f, pk=0.f, pv=0.f;
        #pragma unroll
        for (int nbl=0;nbl<4;nbl++){
            float qv=acc[0][nbl][r], kv=acc[1][nbl][r], vv=acc[2][nbl][r];
            ps += qv*kv; pk += kv*kv; pv += vv*vv;
        }
        #pragma unroll
        for (int off=1; off<16; off<<=1){
            ps += __shfl_xor(ps, off, 64);
            pk += __shfl_xor(pk, off, 64);
            pv += __shfl_xor(pv, off, 64);
        }
        simr[r]=ps; k2r[r]=pk; v2r[r]=pv;
    }
    float qksv = qks[hd];
    #pragma unroll
    for (int r=0;r<4;r++){
        int t = mb*16 + quad*4 + r;
        float invk = 1.f/fmaxf(sqrtf(k2r[r]), 1e-12f);
        float invv = 1.f/fmaxf(sqrtf(v2r[r]), 1e-12f);
        int ST = t>>6, ksb = (t>>5)&1, j = t&7;
        int rowf = ((t>>3)&3)*16 + lm;
        #pragma unroll
        for (int nbl=0;nbl<4;nbl++){
            int frag = ksb*2048 + nbl*512 + rowf*8 + j;
            Upk[((hd*16)+ST)*4096 + frag]     = f2bf(acc[2][nbl][r]*invv);  // v
            Upk[(((8+hd)*16)+ST)*4096 + frag] = f2bf(acc[1][nbl][r]*invk);  // k
            int d = nbl*16 + lm;
            int ks2 = d>>5, j2 = d&7, fl2 = ((d>>3)&3)*16 + (t&15);
            Qpk[((hd*64+mb)*2+ks2)*512 + fl2*8 + j2] = f2bf(acc[0][nbl][r]);
        }
        if (lm==0) simg[hd*Ll + t] = simr[r]*qksv;
    }
}

// ---------- conv phase: one 64-row t-tile T (steps 0..T), both tensors, 3 kf ----------
__device__ __forceinline__ void conv_phase(
    int T, int kf0, int hd,
    const unsigned short* __restrict__ Fpk16,
    const unsigned short* __restrict__ Uv, const unsigned short* __restrict__ Uk,
    const unsigned short* __restrict__ Mh,
    unsigned short* __restrict__ vcb, unsigned short* __restrict__ kcb,
    float* __restrict__ logits, unsigned short* lds,
    int tid, int w, int lane)
{
    int quad = lane>>4, lm = lane&15;
    f32x4 acc[3][2][4];   // [kf][tz][nb]
    #pragma unroll
    for (int kf=0;kf<3;kf++)
        #pragma unroll
        for (int tz=0;tz<2;tz++)
            #pragma unroll
            for (int nb=0;nb<4;nb++) acc[kf][tz][nb]=(f32x4){0.f,0.f,0.f,0.f};

    __syncthreads();   // protect LDS from previous phase's reads
    {
        sh8 v0=*(const sh8*)(Uv+tid*8), v1=*(const sh8*)(Uv+(tid+256)*8);
        sh8 k0=*(const sh8*)(Uk+tid*8), k1=*(const sh8*)(Uk+(tid+256)*8);
        *(sh8*)(&lds[tid*8])=v0; *(sh8*)(&lds[(tid+256)*8])=v1;
        *(sh8*)(&lds[4096+tid*8])=k0; *(sh8*)(&lds[4096+(tid+256)*8])=k1;
    }
    for (int ST=0; ST<=T; ST++){
        sh8 nv0,nv1,nk0,nk1;
        bool more = (ST < T);
        if (more){
            const unsigned short* Uvn = Uv + (ST+1)*4096;
            const unsigned short* Ukn = Uk + (ST+1)*4096;
            nv0=*(const sh8*)(Uvn+tid*8); nv1=*(const sh8*)(Uvn+(tid+256)*8);
            nk0=*(const sh8*)(Ukn+tid*8); nk1=*(const sh8*)(Ukn+(tid+256)*8);
        }
        int d16 = 4*(T-ST) + w;
        sh8 a[3][2];
        #pragma unroll
        for (int kf=0;kf<3;kf++)
            #pragma unroll
            for (int ks=0;ks<2;ks++)
                a[kf][ks] = *(const sh8*)(Fpk16 + ((kf0+kf)*64 + d16)*1024 + ks*512 + lane*8);
        __syncthreads();
        const unsigned short* Bb = &lds[(ST&1)*8192];
        #pragma unroll
        for (int ks=0;ks<2;ks++)
            #pragma unroll
            for (int nb=0;nb<4;nb++){
                sh8 bv = *(const sh8*)(Bb + ks*2048 + nb*512 + lane*8);
                sh8 bk = *(const sh8*)(Bb + 4096 + ks*2048 + nb*512 + lane*8);
                #pragma unroll
                for (int kf=0;kf<3;kf++){
                    acc[kf][0][nb] = __builtin_amdgcn_mfma_f32_16x16x32_bf16(
                        a[kf][ks], bv, acc[kf][0][nb], 0,0,0);
                    acc[kf][1][nb] = __builtin_amdgcn_mfma_f32_16x16x32_bf16(
                        a[kf][ks], bk, acc[kf][1][nb], 0,0,0);
                }
            }
        if (more){
            unsigned short* Bn = &lds[((ST+1)&1)*8192];
            *(sh8*)(Bn+tid*8)=nv0; *(sh8*)(Bn+(tid+256)*8)=nv1;
            *(sh8*)(Bn+4096+tid*8)=nk0; *(sh8*)(Bn+4096+(tid+256)*8)=nk1;
        }
    }
    // epilogue: per kf: stage bf16 (stride 72), global write, P=kc@M^T, dot vc
    float logacc[4] = {0.f,0.f,0.f,0.f};
    #pragma unroll
    for (int kf=0;kf<3;kf++){
        __syncthreads();
        #pragma unroll
        for (int tz=0;tz<2;tz++)
            #pragma unroll
            for (int nb=0;nb<4;nb++)
                #pragma unroll
                for (int r=0;r<4;r++){
                    int tl = w*16 + quad*4 + r;
                    lds[tz*4608 + tl*72 + nb*16 + lm] = f2bf(acc[kf][tz][nb][r]);
                }
        __syncthreads();
        #pragma unroll
        for (int tz=0;tz<2;tz++){
            unsigned short* dst = tz ? kcb : vcb;
            #pragma unroll
            for (int it=0; it<2; it++){
                int idx = tid + it*256;
                int row = idx>>3, seg = idx&7;
                sh8 vv = *(const sh8*)(&lds[tz*4608 + row*72 + seg*8]);
                *(sh8*)(dst + ((hd*Ll + T*64 + row)*KF + kf0+kf)*64 + seg*8) = vv;
            }
        }
        f32x4 accp[4];
        #pragma unroll
        for (int nb=0;nb<4;nb++) accp[nb]=(f32x4){0.f,0.f,0.f,0.f};
        #pragma unroll
        for (int ks=0;ks<2;ks++){
            sh8 a2 = *(const sh8*)(&lds[4608 + (w*16+lm)*72 + ks*32 + quad*8]);
            #pragma unroll
            for (int nb=0;nb<4;nb++){
                sh8 bm = *(const sh8*)(Mh + (nb*2+ks)*512 + lane*8);
                accp[nb] = __builtin_amdgcn_mfma_f32_16x16x32_bf16(a2, bm, accp[nb], 0,0,0);
            }
        }
        #pragma unroll
        for (int r=0;r<4;r++){
            int rloc = w*16 + quad*4 + r;
            float s = 0.f;
            #pragma unroll
            for (int nb=0;nb<4;nb++)
                s += accp[nb][r]*bf2f(lds[rloc*72 + nb*16 + lm]);
            logacc[r] += s;
        }
    }
    #pragma unroll
    for (int r=0;r<4;r++){
        float s = logacc[r];
        s += __shfl_xor(s, 1, 64);
        s += __shfl_xor(s, 2, 64);
        s += __shfl_xor(s, 4, 64);
        s += __shfl_xor(s, 8, 64);
        if (lm==0)
            atomicAdd(&logits[hd*Ll + T*64 + w*16 + quad*4 + r], s);
    }
}

// grid (8 pairs, 8 kf-triples, 8 hd) = 512 equal blocks (tiles 15-p and p)
__global__ __launch_bounds__(256,2) void convf_kernel(
    const unsigned short* __restrict__ Fpk16, const unsigned short* __restrict__ Upk,
    const unsigned short* __restrict__ Mpk,
    unsigned short* __restrict__ vcb, unsigned short* __restrict__ kcb,
    float* __restrict__ logits)
{
    __shared__ unsigned short lds[16384];   // 32 KB
    int p = blockIdx.x, kf0 = blockIdx.y*3, hd = blockIdx.z;
    int tid=threadIdx.x, w=tid>>6, lane=tid&63;
    const unsigned short* Uv = Upk + (hd*16)*4096;
    const unsigned short* Uk = Upk + ((8+hd)*16)*4096;
    const unsigned short* Mh = Mpk + hd*4096;
    conv_phase(15-p, kf0, hd, Fpk16, Uv, Uk, Mh, vcb, kcb, logits, lds, tid, w, lane);
    conv_phase(p,    kf0, hd, Fpk16, Uv, Uk, Mh, vcb, kcb, logits, lds, tid, w, lane);
}

// scan (fused gates): logits -> gates, factor
__global__ __launch_bounds__(256) void scan_kernel(
    const float* __restrict__ simg, const float* __restrict__ logits,
    const float* __restrict__ bg, float* __restrict__ gates, float* __restrict__ factor)
{
    int hd=blockIdx.x, tid=threadIdx.x;
    __shared__ float sm[256], ssc[256], sg[256];
    float bgv = bg[0];
    float simv[4], m_loc[4], s_loc[4], g_loc[4];
    float m = -__builtin_inff(), s = 0.f, g = 0.f;
    for(int e=0;e<4;e++){
        int ix = hd*Ll + tid*4 + e;
        simv[e] = simg[ix];
        float lg = logits[ix] + bgv;
        float r = fmaxf(lg, 0.f);
        float gv = r*r + EPSf;
        gates[ix] = gv;
        float mn = fmaxf(m, simv[e]);
        s = s*__expf(m-mn) + __expf(simv[e]-mn);
        m = mn; g += gv;
        m_loc[e]=m; s_loc[e]=s; g_loc[e]=g;
    }
    sm[tid]=m; ssc[tid]=s; sg[tid]=g;
    __syncthreads();
    for(int off=1; off<256; off<<=1){
        float pm=0, ps=0, pg=0; bool has = (tid>=off);
        if(has){ pm=sm[tid-off]; ps=ssc[tid-off]; pg=sg[tid-off]; }
        __syncthreads();
        if(has){
            float mn=fmaxf(pm, sm[tid]);
            float sn=ps*__expf(pm-mn) + ssc[tid]*__expf(sm[tid]-mn);
            sm[tid]=mn; ssc[tid]=sn; sg[tid]=pg+sg[tid];
        }
        __syncthreads();
    }
    float pm=-__builtin_inff(), ps=0.f, pg=0.f;
    if (tid>0){ pm=sm[tid-1]; ps=ssc[tid-1]; pg=sg[tid-1]; }
    for(int e=0;e<4;e++){
        float mn=fmaxf(pm, m_loc[e]);
        float sn=ps*__expf(pm-mn) + s_loc[e]*__expf(m_loc[e]-mn);
        float gn=pg + g_loc[e];
        float sw = __expf(simv[e]-mn)/(sn+EPSf);
        float silu = sw/(1.f+__expf(-sw));
        factor[hd*Ll + tid*4 + e] = (1.f+silu)/(gn+EPSf);
    }
}

// ---------- fused phase3 + chunkz (MFMA); cpart via atomic accumulate; czp bf16 ----------
#define VTS 68
#define ASS 72
__global__ __launch_bounds__(256) void p3cz_kernel(
    const unsigned short* __restrict__ Qpk,
    const unsigned short* __restrict__ vcb, const unsigned short* __restrict__ kcb,
    const float* __restrict__ gates, float* __restrict__ cpart,
    unsigned short* __restrict__ czp)
{
    __shared__ unsigned short VT[64*VTS];
    __shared__ unsigned short KT[64*VTS];
    __shared__ unsigned short As[4][16*ASS];
    __shared__ unsigned short Vraw[64*72];
    __shared__ float gl[16];
    int tid=threadIdx.x, w=tid>>6, lane=tid&63;
    int quad=lane>>4, lm=lane&15;
    int c=blockIdx.x, qq=blockIdx.y, hd=blockIdx.z;
    int T0=c*64, tq0=T0+qq*16, RQ0=tq0*KF;
    if (tid<16) gl[tid]=gates[hd*Ll+tq0+tid];
    sh8 aq[2];
    {
        const unsigned short* qb = Qpk + ((hd*64 + (c*4+w))*2)*512;
        aq[0] = *(const sh8*)(qb + lane*8);
        aq[1] = *(const sh8*)(qb + 512 + lane*8);
    }
    f32x4 ctx[4], cz[4];
    #pragma unroll
    for (int nb=0;nb<4;nb++){ ctx[nb]=(f32x4){0,0,0,0}; cz[nb]=(f32x4){0,0,0,0}; }
    int t_g = T0 + w*16 + quad*4;
    int rp = tid>>3, e0 = (tid&7)*8, r0 = rp*2;

    sh8 pv0, pv1, pk0, pk1;
    {
        const unsigned short* vrow = vcb + (hd*LK + RQ0)*64;
        const unsigned short* krow = kcb + (hd*LK + RQ0)*64;
        pv0 = *(const sh8*)(vrow + r0*64 + e0);
        pv1 = *(const sh8*)(vrow + (r0+1)*64 + e0);
        pk0 = *(const sh8*)(krow + r0*64 + e0);
        pk1 = *(const sh8*)(krow + (r0+1)*64 + e0);
    }
    for (int sub=0; sub<6; sub++){
        int RB = RQ0 + sub*64;
        __syncthreads();
        {
            float g0 = gl[(RB + r0)/KF - tq0];
            float g1 = gl[(RB + r0 + 1)/KF - tq0];
            *(sh8*)(&Vraw[r0*72 + e0]) = pv0;
            *(sh8*)(&Vraw[(r0+1)*72 + e0]) = pv1;
            #pragma unroll
            for (int j=0;j<8;j++){
                unsigned int pv = (unsigned int)f2bf(bf2f((unsigned short)pv0[j])*g0)
                                | ((unsigned int)f2bf(bf2f((unsigned short)pv1[j])*g1)<<16);
                *(unsigned int*)(&VT[(e0+j)*VTS + r0]) = pv;
                unsigned int pk = (unsigned int)(unsigned short)pk0[j]
                                | ((unsigned int)(unsigned short)pk1[j]<<16);
                *(unsigned int*)(&KT[(e0+j)*VTS + r0]) = pk;
            }
        }
        if (sub < 5){
            const unsigned short* vrow = vcb + (hd*LK + RB + 64)*64;
            const unsigned short* krow = kcb + (hd*LK + RB + 64)*64;
            pv0 = *(const sh8*)(vrow + r0*64 + e0);
            pv1 = *(const sh8*)(vrow + (r0+1)*64 + e0);
            pk0 = *(const sh8*)(krow + r0*64 + e0);
            pk1 = *(const sh8*)(krow + (r0+1)*64 + e0);
        }
        __syncthreads();
        f32x4 S[4];
        #pragma unroll
        for (int nb=0;nb<4;nb++) S[nb]=(f32x4){0,0,0,0};
        #pragma unroll
        for (int ks=0;ks<2;ks++){
            #pragma unroll
            for (int nb=0;nb<4;nb++){
                sh8 b = *(const sh8*)(&Vraw[(nb*16+lm)*72 + ks*32 + quad*8]);
                S[nb] = __builtin_amdgcn_mfma_f32_16x16x32_bf16(aq[ks], b, S[nb], 0,0,0);
            }
        }
        #pragma unroll
        for (int nb=0;nb<4;nb++){
            int row_l = nb*16+lm;
            int tp = (RB + row_l)/KF;
            float g = gl[tp - tq0];
            #pragma unroll
            for (int r=0;r<4;r++){
                float v = (t_g + r >= tp) ? S[nb][r]*g : 0.f;
                As[w][(quad*4+r)*ASS + row_l] = f2bf(v);
            }
        }
        #pragma unroll
        for (int ks=0;ks<2;ks++){
            sh8 a2 = *(const sh8*)(&As[w][lm*ASS + ks*32 + quad*8]);
            sh8 av = ld8_8B(&VT[(w*16+lm)*VTS + ks*32 + quad*8]);
            #pragma unroll
            for (int nb=0;nb<4;nb++){
                sh8 bk = ld8_8B(&KT[(nb*16+lm)*VTS + ks*32 + quad*8]);
                ctx[nb] = __builtin_amdgcn_mfma_f32_16x16x32_bf16(a2, bk, ctx[nb], 0,0,0);
                cz[nb]  = __builtin_amdgcn_mfma_f32_16x16x32_bf16(av, bk, cz[nb], 0,0,0);
            }
        }
    }
    #pragma unroll
    for (int nb=0;nb<4;nb++){
        #pragma unroll
        for (int r=0;r<4;r++){
            atomicAdd(&cpart[(hd*Ll + t_g + r)*64 + nb*16+lm], ctx[nb][r]);
        }
    }
    int ob = ((hd*16+c)*4+qq)*4096;
    #pragma unroll
    for (int nb=0;nb<4;nb++){
        #pragma unroll
        for (int r=0;r<4;r++){
            czp[ob + (w*16+quad*4+r)*64 + nb*16+lm] = f2bf(cz[nb][r]);
        }
    }
}

// combine (MFMA) with fused exclusive chunk prefix:
// Cpk = factor * ( Qpk @ S0(czp prefix) + cpart )
__global__ __launch_bounds__(256) void combine_kernel(
    const unsigned short* __restrict__ Qpk, const unsigned short* __restrict__ czp,
    const float* __restrict__ cpart, const float* __restrict__ factor,
    unsigned short* __restrict__ Cpk)
{
    __shared__ unsigned short sb[4096];
    int c=blockIdx.x, hd=blockIdx.y;
    int tid=threadIdx.x, wid=tid>>6, lane=tid&63, quad=lane>>4, lm=lane&15;
    // build S0 (exclusive prefix over chunks) in B-frag layout in LDS
    for (int it=0; it<16; it++){
        int de = tid + it*256;              // d*64 + e
        float a = 0.f;
        const unsigned short* base = czp + (hd*64)*4096 + de;
        for (int cc=0; cc<c; cc++){
            const unsigned short* b4 = base + cc*4*4096;
            a += bf2f(b4[0]) + bf2f(b4[4096]) + bf2f(b4[8192]) + bf2f(b4[12288]);
        }
        int d = de>>6, e = de&63;
        int frag = (d>>5)*2048 + (e>>4)*512 + ((((d>>3)&3)*16)+(e&15))*8 + (d&7);
        sb[frag] = f2bf(a);
    }
    __syncthreads();
    int mb = c*4 + wid;
    sh8 aq0 = *(const sh8*)(Qpk + ((hd*64+mb)*2)*512 + lane*8);
    sh8 aq1 = *(const sh8*)(Qpk + ((hd*64+mb)*2+1)*512 + lane*8);
    f32x4 acc[4];
    #pragma unroll
    for (int nb=0;nb<4;nb++) acc[nb]=(f32x4){0.f,0.f,0.f,0.f};
    #pragma unroll
    for (int ks=0;ks<2;ks++){
        sh8 a = ks ? aq1 : aq0;
        #pragma unroll
        for (int nb=0;nb<4;nb++){
            sh8 b = *(const sh8*)(sb + ks*2048 + nb*512 + lane*8);
            acc[nb] = __builtin_amdgcn_mfma_f32_16x16x32_bf16(a, b, acc[nb], 0,0,0);
        }
    }
    float fv[4];
    #pragma unroll
    for (int r=0;r<4;r++) fv[r] = factor[hd*Ll + mb*16 + quad*4 + r];
    #pragma unroll
    for (int nb=0;nb<4;nb++){
        int e = nb*16 + lm;
        int dim = hd*64 + e;
        int ks2 = dim>>5, koff = dim&31, qd = koff>>3, jj = koff&7;
        #pragma unroll
        for (int r=0;r<4;r++){
            int t = mb*16 + quad*4 + r;
            float v = acc[nb][r] + cpart[(hd*Ll + t)*64 + e];
            v *= fv[r];
            Cpk[((t>>4)*16 + ks2)*512 + qd*128 + (t&15)*8 + jj] = f2bf(v);
        }
    }
}

// out = Cpk @ Wopk + bo
__global__ __launch_bounds__(256) void outprojm_kernel(
    const unsigned short* __restrict__ Cpk, const unsigned short* __restrict__ Wopk,
    const float* __restrict__ bo, float* __restrict__ out)
{
    int mt=blockIdx.x, nt=blockIdx.y;
    int tid=threadIdx.x, wid=tid>>6, lane=tid&63;
    int mb=mt*4+wid;
    f32x4 acc[4];
    #pragma unroll
    for (int nb=0;nb<4;nb++) acc[nb]=(f32x4){0.f,0.f,0.f,0.f};
    for (int ks=0;ks<16;ks++){
        sh8 a = *(const sh8*)(Cpk + (mb*16+ks)*512 + lane*8);
        #pragma unroll
        for (int nb2=0;nb2<4;nb2++){
            sh8 b = *(const sh8*)(Wopk + ((nt*4+nb2)*16+ks)*512 + lane*8);
            acc[nb2] = __builtin_amdgcn_mfma_f32_16x16x32_bf16(a, b, acc[nb2], 0,0,0);
        }
    }
    int quad=lane>>4, col=lane&15;
    #pragma unroll
    for (int nb2=0;nb2<4;nb2++){
        int n = nt*64 + nb2*16 + col;
        float bval = bo[n];
        #pragma unroll
        for (int r=0;r<4;r++){
            out[(mb*16+quad*4+r)*Dm + n] = acc[nb2][r] + bval;
        }
    }
}

extern "C" void kernel_launch(void* const* d_in, const int* in_sizes, int n_in,
                              void* d_out, int out_size, void* d_ws, size_t ws_size,
                              hipStream_t stream)
{
    (void)in_sizes; (void)n_in; (void)out_size; (void)ws_size;
    const float* x   =(const float*)d_in[0];
    const float* Wq  =(const float*)d_in[1];
    const float* bq  =(const float*)d_in[2];
    const float* Wk  =(const float*)d_in[3];
    const float* bk  =(const float*)d_in[4];
    const float* Wv  =(const float*)d_in[5];
    const float* bv  =(const float*)d_in[6];
    const float* Wo  =(const float*)d_in[7];
    const float* bo  =(const float*)d_in[8];
    const float* Wg  =(const float*)d_in[9];
    const float* bg  =(const float*)d_in[10];
    const float* kvs =(const float*)d_in[11];
    const float* qks =(const float*)d_in[12];
    const float* filt=(const float*)d_in[13];
    float* ws = (float*)d_ws;
    float* simg  = ws+OFF_SIM;
    float* logits= ws+OFF_LOGITS;
    float* gates = ws+OFF_GATES;
    float* factor= ws+OFF_FACTOR;
    float* cpart = ws+OFF_CPART;
    unsigned short* vcb  = (unsigned short*)(ws + OFF_VCB);
    unsigned short* kcb  = (unsigned short*)(ws + OFF_KCB);
    unsigned short* Qpk  = (unsigned short*)(ws + OFF_QPK);
    unsigned short* Mpk  = (unsigned short*)(ws + OFF_MPK);
    unsigned short* Wopk = (unsigned short*)(ws + OFF_WOPK);
    unsigned short* Cpk  = (unsigned short*)(ws + OFF_CPK);
    unsigned short* czp  = (unsigned short*)(ws + OFF_CZP);
    unsigned short* Fpk16= (unsigned short*)(ws + OFF_FPK_F);
    unsigned short* Upk  = (unsigned short*)(ws + OFF_UPK_F);
    unsigned short* Apk  = (unsigned short*)(ws + OFF_APK_F);
    unsigned short* Bpk  = (unsigned short*)(ws + OFF_BPK_F);
    float* out   = (float*)d_out;

    pack_all_kernel<<<dim3(361),    256,0,stream>>>(x,Wq,Wk,Wv,Wo,kvs,Wg,filt,
                                                    Apk,Bpk,Wopk,Mpk,Fpk16,logits,cpart);
    qkvn_kernel   <<<dim3(64,8),    64, 0,stream>>>(Apk,Bpk,bq,bk,bv,qks,simg,Upk,Qpk);
    convf_kernel  <<<dim3(8,8,8),   256,0,stream>>>(Fpk16,Upk,Mpk,vcb,kcb,logits);
    scan_kernel   <<<dim3(8),       256,0,stream>>>(simg,logits,bg,gates,factor);
    p3cz_kernel   <<<dim3(16,4,8),  256,0,stream>>>(Qpk,vcb,kcb,gates,cpart,czp);
    combine_kernel<<<dim3(16,8),    256,0,stream>>>(Qpk,czp,cpart,factor,Cpk);
    outprojm_kernel<<<dim3(16,8),   256,0,stream>>>(Cpk,Wopk,bo,out);
}

// Round 11
// 165.475 us; speedup vs baseline: 1.3981x; 1.3981x over previous
//
#include <hip/hip_runtime.h>
#include <math.h>

#define Hh 8
#define Ll 1024
#define KF 24
#define Dm 512
#define EPSf 1e-5f
#define LK (Ll*KF)   // 24576 rows (t,kf) per head

typedef __attribute__((ext_vector_type(8))) short sh8;
typedef __attribute__((ext_vector_type(4))) short sh4;
typedef __attribute__((ext_vector_type(4))) float f32x4;

// ---- workspace offsets (floats) ----
#define OFF_SIM    1572864
#define OFF_LOGITS 1581056
#define OFF_GATES  1589248
#define OFF_FACTOR 1597440
#define OFF_VCB    1605632     // bf16 vc
#define OFF_KCB    7897088     // bf16 kc
#define OFF_QPK    14188544    // bf16 Q A-frags
#define OFF_MPK    14450688    // bf16 M B-frags
#define OFF_WOPK   14467072    // bf16 Wo B-frags
#define OFF_CPK    14598144    // bf16 ctxt A-frags
#define OFF_CZP    26771456    // bf16 chunk partials (ushort)
#define OFF_S0     28868608    // bf16 S0 B-frags
#define OFF_CPART  29392896    // fp32 accumulated cpart (2 MB)
// pack overlays inside CZP region (all consumed before p3cz writes czp):
#define OFF_FPK_F  26771456    // Fpk16: 24*64*1024 ush
#define OFF_UPK_F  27607040
#define OFF_APK_F  28131328
#define OFF_BPK_F  28393472

__device__ inline unsigned short f2bf(float x){
    unsigned int u = __float_as_uint(x);
    unsigned int r = (u + 0x7fffu + ((u>>16)&1u)) >> 16;
    return (unsigned short)r;
}
__device__ inline float bf2f(unsigned short u){ return __uint_as_float(((unsigned int)u)<<16); }
__device__ inline sh8 ld8_8B(const unsigned short* p){
    union { sh8 s; sh4 h[2]; } u;
    u.h[0] = *(const sh4*)(p);
    u.h[1] = *(const sh4*)(p+4);
    return u.s;
}

// ---------- fused packing kernel ----------
// 0..63: x A-frags | 64..159: W qkv B-frags | 160..191: Wo | 192..199: M
// 200..295: Fpk16 (LDS-staged filt column) | 296: zero logits | 297..360: zero cpart
__global__ __launch_bounds__(256) void pack_all_kernel(
    const float* __restrict__ x,
    const float* __restrict__ Wq, const float* __restrict__ Wk, const float* __restrict__ Wv,
    const float* __restrict__ Wo, const float* __restrict__ kvs, const float* __restrict__ Wg,
    const float* __restrict__ filt,
    unsigned short* __restrict__ Apk, unsigned short* __restrict__ Bpk,
    unsigned short* __restrict__ Wopk, unsigned short* __restrict__ Mpk,
    unsigned short* __restrict__ Fpk16, float* __restrict__ logits,
    float* __restrict__ cpart)
{
    __shared__ float fl[1024];
    int bid = blockIdx.x, tid = threadIdx.x;
    if (bid < 64){
        int mb = bid;
        for (int ks=0; ks<16; ks++){
            #pragma unroll
            for (int p=0;p<2;p++){
                int e = tid + p*256;
                int lane = e>>3, j = e&7;
                int m = mb*16 + (lane&15);
                int k = ks*32 + ((lane>>4)&3)*8 + j;
                Apk[(mb*16+ks)*512 + e] = f2bf(x[m*Dm + k]);
            }
        }
    } else if (bid < 160){
        int nb = bid - 64;
        int n0 = nb*16;
        int mm = n0>>9;
        const float* W = (mm==0)?Wq:((mm==1)?Wk:Wv);
        int coff = n0 & 511;
        for (int ks=0; ks<16; ks++){
            #pragma unroll
            for (int p=0;p<2;p++){
                int e = tid + p*256;
                int lane = e>>3, j = e&7;
                int kk = ks*32 + ((lane>>4)&3)*8 + j;
                Bpk[(nb*16+ks)*512 + e] = f2bf(W[kk*Dm + coff + (lane&15)]);
            }
        }
    } else if (bid < 192){
        int nb = bid - 160;
        int n0 = nb*16;
        for (int ks=0; ks<16; ks++){
            #pragma unroll
            for (int p=0;p<2;p++){
                int e = tid + p*256;
                int lane = e>>3, j = e&7;
                int kk = ks*32 + ((lane>>4)&3)*8 + j;
                Wopk[(nb*16+ks)*512 + e] = f2bf(Wo[kk*Dm + n0 + (lane&15)]);
            }
        }
    } else if (bid < 200){
        int hd = bid - 192;
        for (int it=0; it<16; it++){
            int idx = tid + it*256;
            int f = idx & 511, ksnb = idx >> 9;
            int nb = ksnb>>1, ks = ksnb&1;
            int lane = f>>3, j = f&7;
            int e = nb*16 + (lane&15);
            int d = ks*32 + ((lane>>4)&3)*8 + j;
            Mpk[hd*4096 + idx] = f2bf(kvs[(hd*64+e)*64 + d]*Wg[e*64+d]);
        }
    } else if (bid < 296){
        int b2 = bid - 200;            // 24 kf x 4 groups
        int kf = b2>>2, g = b2&3;
        for (int i=tid; i<1024; i+=256) fl[i] = filt[i*KF + kf];
        __syncthreads();
        for (int ti=0; ti<16; ti++){
            int d16 = g*16 + ti;
            unsigned short* dst = Fpk16 + (kf*64 + d16)*1024;
            #pragma unroll
            for (int p2=0;p2<4;p2++){
                int e = tid + p2*256;
                int ks = e>>9, f = e&511;
                int lane = f>>3, j = f&7;
                int m = lane&15;
                int k = ks*32 + ((lane>>4)&3)*8 + j;
                int fidx = 16*d16 + m - k;
                float v = (fidx>=0) ? fl[fidx] : 0.0f;
                dst[e] = f2bf(v);
            }
        }
    } else if (bid == 296){
        for (int i=tid; i<Hh*Ll; i+=256) logits[i] = 0.f;
    } else {
        int zb = bid - 297;            // 64 blocks x 8192 floats = 512K floats
        int base = zb*8192;
        for (int i=tid; i<8192; i+=256) cpart[base+i] = 0.f;
    }
}

// ---------- fused QKV GEMM + sim + normalize + pack ----------
__global__ __launch_bounds__(64) void qkvn_kernel(
    const unsigned short* __restrict__ Apk, const unsigned short* __restrict__ Bpk,
    const float* __restrict__ bq, const float* __restrict__ bk, const float* __restrict__ bv,
    const float* __restrict__ qks, float* __restrict__ simg,
    unsigned short* __restrict__ Upk, unsigned short* __restrict__ Qpk)
{
    int mb = blockIdx.x, hd = blockIdx.y;
    int lane = threadIdx.x, quad = lane>>4, lm = lane&15;
    f32x4 acc[3][4];
    #pragma unroll
    for (int mm=0;mm<3;mm++)
        #pragma unroll
        for (int nbl=0;nbl<4;nbl++) acc[mm][nbl]=(f32x4){0.f,0.f,0.f,0.f};
    for (int ks=0; ks<16; ks++){
        sh8 a = *(const sh8*)(Apk + (mb*16+ks)*512 + lane*8);
        #pragma unroll
        for (int mm=0;mm<3;mm++)
            #pragma unroll
            for (int nbl=0;nbl<4;nbl++){
                sh8 b = *(const sh8*)(Bpk + ((mm*32 + hd*4 + nbl)*16 + ks)*512 + lane*8);
                acc[mm][nbl] = __builtin_amdgcn_mfma_f32_16x16x32_bf16(a, b, acc[mm][nbl], 0,0,0);
            }
    }
    #pragma unroll
    for (int nbl=0;nbl<4;nbl++){
        float bqv = bq[hd*64 + nbl*16 + lm];
        float bkv = bk[hd*64 + nbl*16 + lm];
        float bvv = bv[hd*64 + nbl*16 + lm];
        #pragma unroll
        for (int r=0;r<4;r++){
            acc[0][nbl][r] += bqv; acc[1][nbl][r] += bkv; acc[2][nbl][r] += bvv;
        }
    }
    float simr[4], k2r[4], v2r[4];
    #pragma unroll
    for (int r=0;r<4;r++){
        float ps=0.f, pk=0.f, pv=0.f;
        #pragma unroll
        for (int nbl=0;nbl<4;nbl++){
            float qv=acc[0][nbl][r], kv=acc[1][nbl][r], vv=acc[2][nbl][r];
            ps += qv*kv; pk += kv*kv; pv += vv*vv;
        }
        #pragma unroll
        for (int off=1; off<16; off<<=1){
            ps += __shfl_xor(ps, off, 64);
            pk += __shfl_xor(pk, off, 64);
            pv += __shfl_xor(pv, off, 64);
        }
        simr[r]=ps; k2r[r]=pk; v2r[r]=pv;
    }
    float qksv = qks[hd];
    #pragma unroll
    for (int r=0;r<4;r++){
        int t = mb*16 + quad*4 + r;
        float invk = 1.f/fmaxf(sqrtf(k2r[r]), 1e-12f);
        float invv = 1.f/fmaxf(sqrtf(v2r[r]), 1e-12f);
        int ST = t>>6, ksb = (t>>5)&1, j = t&7;
        int rowf = ((t>>3)&3)*16 + lm;
        #pragma unroll
        for (int nbl=0;nbl<4;nbl++){
            int frag = ksb*2048 + nbl*512 + rowf*8 + j;
            Upk[((hd*16)+ST)*4096 + frag]     = f2bf(acc[2][nbl][r]*invv);  // v
            Upk[(((8+hd)*16)+ST)*4096 + frag] = f2bf(acc[1][nbl][r]*invk);  // k
            int d = nbl*16 + lm;
            int ks2 = d>>5, j2 = d&7, fl2 = ((d>>3)&3)*16 + (t&15);
            Qpk[((hd*64+mb)*2+ks2)*512 + fl2*8 + j2] = f2bf(acc[0][nbl][r]);
        }
        if (lm==0) simg[hd*Ll + t] = simr[r]*qksv;
    }
}

// ---------- conv phase: one 64-row t-tile T (steps 0..T), both tensors, 3 kf ----------
__device__ __forceinline__ void conv_phase(
    int T, int kf0, int hd,
    const unsigned short* __restrict__ Fpk16,
    const unsigned short* __restrict__ Uv, const unsigned short* __restrict__ Uk,
    const unsigned short* __restrict__ Mh,
    unsigned short* __restrict__ vcb, unsigned short* __restrict__ kcb,
    float* __restrict__ logits, unsigned short* lds,
    int tid, int w, int lane)
{
    int quad = lane>>4, lm = lane&15;
    f32x4 acc[3][2][4];   // [kf][tz][nb]
    #pragma unroll
    for (int kf=0;kf<3;kf++)
        #pragma unroll
        for (int tz=0;tz<2;tz++)
            #pragma unroll
            for (int nb=0;nb<4;nb++) acc[kf][tz][nb]=(f32x4){0.f,0.f,0.f,0.f};

    __syncthreads();   // protect LDS from previous phase's reads
    {
        sh8 v0=*(const sh8*)(Uv+tid*8), v1=*(const sh8*)(Uv+(tid+256)*8);
        sh8 k0=*(const sh8*)(Uk+tid*8), k1=*(const sh8*)(Uk+(tid+256)*8);
        *(sh8*)(&lds[tid*8])=v0; *(sh8*)(&lds[(tid+256)*8])=v1;
        *(sh8*)(&lds[4096+tid*8])=k0; *(sh8*)(&lds[4096+(tid+256)*8])=k1;
    }
    for (int ST=0; ST<=T; ST++){
        sh8 nv0,nv1,nk0,nk1;
        bool more = (ST < T);
        if (more){
            const unsigned short* Uvn = Uv + (ST+1)*4096;
            const unsigned short* Ukn = Uk + (ST+1)*4096;
            nv0=*(const sh8*)(Uvn+tid*8); nv1=*(const sh8*)(Uvn+(tid+256)*8);
            nk0=*(const sh8*)(Ukn+tid*8); nk1=*(const sh8*)(Ukn+(tid+256)*8);
        }
        int d16 = 4*(T-ST) + w;
        sh8 a[3][2];
        #pragma unroll
        for (int kf=0;kf<3;kf++)
            #pragma unroll
            for (int ks=0;ks<2;ks++)
                a[kf][ks] = *(const sh8*)(Fpk16 + ((kf0+kf)*64 + d16)*1024 + ks*512 + lane*8);
        __syncthreads();
        const unsigned short* Bb = &lds[(ST&1)*8192];
        #pragma unroll
        for (int ks=0;ks<2;ks++)
            #pragma unroll
            for (int nb=0;nb<4;nb++){
                sh8 bv = *(const sh8*)(Bb + ks*2048 + nb*512 + lane*8);
                sh8 bk = *(const sh8*)(Bb + 4096 + ks*2048 + nb*512 + lane*8);
                #pragma unroll
                for (int kf=0;kf<3;kf++){
                    acc[kf][0][nb] = __builtin_amdgcn_mfma_f32_16x16x32_bf16(
                        a[kf][ks], bv, acc[kf][0][nb], 0,0,0);
                    acc[kf][1][nb] = __builtin_amdgcn_mfma_f32_16x16x32_bf16(
                        a[kf][ks], bk, acc[kf][1][nb], 0,0,0);
                }
            }
        if (more){
            unsigned short* Bn = &lds[((ST+1)&1)*8192];
            *(sh8*)(Bn+tid*8)=nv0; *(sh8*)(Bn+(tid+256)*8)=nv1;
            *(sh8*)(Bn+4096+tid*8)=nk0; *(sh8*)(Bn+4096+(tid+256)*8)=nk1;
        }
    }
    // epilogue: per kf: stage bf16 (stride 72), global write, P=kc@M^T, dot vc
    float logacc[4] = {0.f,0.f,0.f,0.f};
    #pragma unroll
    for (int kf=0;kf<3;kf++){
        __syncthreads();
        #pragma unroll
        for (int tz=0;tz<2;tz++)
            #pragma unroll
            for (int nb=0;nb<4;nb++)
                #pragma unroll
                for (int r=0;r<4;r++){
                    int tl = w*16 + quad*4 + r;
                    lds[tz*4608 + tl*72 + nb*16 + lm] = f2bf(acc[kf][tz][nb][r]);
                }
        __syncthreads();
        #pragma unroll
        for (int tz=0;tz<2;tz++){
            unsigned short* dst = tz ? kcb : vcb;
            #pragma unroll
            for (int it=0; it<2; it++){
                int idx = tid + it*256;
                int row = idx>>3, seg = idx&7;
                sh8 vv = *(const sh8*)(&lds[tz*4608 + row*72 + seg*8]);
                *(sh8*)(dst + ((hd*Ll + T*64 + row)*KF + kf0+kf)*64 + seg*8) = vv;
            }
        }
        f32x4 accp[4];
        #pragma unroll
        for (int nb=0;nb<4;nb++) accp[nb]=(f32x4){0.f,0.f,0.f,0.f};
        #pragma unroll
        for (int ks=0;ks<2;ks++){
            sh8 a2 = *(const sh8*)(&lds[4608 + (w*16+lm)*72 + ks*32 + quad*8]);
            #pragma unroll
            for (int nb=0;nb<4;nb++){
                sh8 bm = *(const sh8*)(Mh + (nb*2+ks)*512 + lane*8);
                accp[nb] = __builtin_amdgcn_mfma_f32_16x16x32_bf16(a2, bm, accp[nb], 0,0,0);
            }
        }
        #pragma unroll
        for (int r=0;r<4;r++){
            int rloc = w*16 + quad*4 + r;
            float s = 0.f;
            #pragma unroll
            for (int nb=0;nb<4;nb++)
                s += accp[nb][r]*bf2f(lds[rloc*72 + nb*16 + lm]);
            logacc[r] += s;
        }
    }
    #pragma unroll
    for (int r=0;r<4;r++){
        float s = logacc[r];
        s += __shfl_xor(s, 1, 64);
        s += __shfl_xor(s, 2, 64);
        s += __shfl_xor(s, 4, 64);
        s += __shfl_xor(s, 8, 64);
        if (lm==0)
            atomicAdd(&logits[hd*Ll + T*64 + w*16 + quad*4 + r], s);
    }
}

// grid (8 pairs, 8 kf-triples, 8 hd) = 512 equal blocks (tiles 15-p and p)
__global__ __launch_bounds__(256,2) void convf_kernel(
    const unsigned short* __restrict__ Fpk16, const unsigned short* __restrict__ Upk,
    const unsigned short* __restrict__ Mpk,
    unsigned short* __restrict__ vcb, unsigned short* __restrict__ kcb,
    float* __restrict__ logits)
{
    __shared__ unsigned short lds[16384];   // 32 KB
    int p = blockIdx.x, kf0 = blockIdx.y*3, hd = blockIdx.z;
    int tid=threadIdx.x, w=tid>>6, lane=tid&63;
    const unsigned short* Uv = Upk + (hd*16)*4096;
    const unsigned short* Uk = Upk + ((8+hd)*16)*4096;
    const unsigned short* Mh = Mpk + hd*4096;
    conv_phase(15-p, kf0, hd, Fpk16, Uv, Uk, Mh, vcb, kcb, logits, lds, tid, w, lane);
    conv_phase(p,    kf0, hd, Fpk16, Uv, Uk, Mh, vcb, kcb, logits, lds, tid, w, lane);
}

// scan (fused gates): logits -> gates, factor
__global__ __launch_bounds__(256) void scan_kernel(
    const float* __restrict__ simg, const float* __restrict__ logits,
    const float* __restrict__ bg, float* __restrict__ gates, float* __restrict__ factor)
{
    int hd=blockIdx.x, tid=threadIdx.x;
    __shared__ float sm[256], ssc[256], sg[256];
    float bgv = bg[0];
    float simv[4], m_loc[4], s_loc[4], g_loc[4];
    float m = -__builtin_inff(), s = 0.f, g = 0.f;
    for(int e=0;e<4;e++){
        int ix = hd*Ll + tid*4 + e;
        simv[e] = simg[ix];
        float lg = logits[ix] + bgv;
        float r = fmaxf(lg, 0.f);
        float gv = r*r + EPSf;
        gates[ix] = gv;
        float mn = fmaxf(m, simv[e]);
        s = s*__expf(m-mn) + __expf(simv[e]-mn);
        m = mn; g += gv;
        m_loc[e]=m; s_loc[e]=s; g_loc[e]=g;
    }
    sm[tid]=m; ssc[tid]=s; sg[tid]=g;
    __syncthreads();
    for(int off=1; off<256; off<<=1){
        float pm=0, ps=0, pg=0; bool has = (tid>=off);
        if(has){ pm=sm[tid-off]; ps=ssc[tid-off]; pg=sg[tid-off]; }
        __syncthreads();
        if(has){
            float mn=fmaxf(pm, sm[tid]);
            float sn=ps*__expf(pm-mn) + ssc[tid]*__expf(sm[tid]-mn);
            sm[tid]=mn; ssc[tid]=sn; sg[tid]=pg+sg[tid];
        }
        __syncthreads();
    }
    float pm=-__builtin_inff(), ps=0.f, pg=0.f;
    if (tid>0){ pm=sm[tid-1]; ps=ssc[tid-1]; pg=sg[tid-1]; }
    for(int e=0;e<4;e++){
        float mn=fmaxf(pm, m_loc[e]);
        float sn=ps*__expf(pm-mn) + s_loc[e]*__expf(m_loc[e]-mn);
        float gn=pg + g_loc[e];
        float sw = __expf(simv[e]-mn)/(sn+EPSf);
        float silu = sw/(1.f+__expf(-sw));
        factor[hd*Ll + tid*4 + e] = (1.f+silu)/(gn+EPSf);
    }
}

// ---------- fused phase3 + chunkz (MFMA); cpart via atomic accumulate; czp bf16 ----------
#define VTS 68
#define ASS 72
__global__ __launch_bounds__(256) void p3cz_kernel(
    const unsigned short* __restrict__ Qpk,
    const unsigned short* __restrict__ vcb, const unsigned short* __restrict__ kcb,
    const float* __restrict__ gates, float* __restrict__ cpart,
    unsigned short* __restrict__ czp)
{
    __shared__ unsigned short VT[64*VTS];
    __shared__ unsigned short KT[64*VTS];
    __shared__ unsigned short As[4][16*ASS];
    __shared__ unsigned short Vraw[64*72];
    __shared__ float gl[16];
    int tid=threadIdx.x, w=tid>>6, lane=tid&63;
    int quad=lane>>4, lm=lane&15;
    int c=blockIdx.x, qq=blockIdx.y, hd=blockIdx.z;
    int T0=c*64, tq0=T0+qq*16, RQ0=tq0*KF;
    if (tid<16) gl[tid]=gates[hd*Ll+tq0+tid];
    sh8 aq[2];
    {
        const unsigned short* qb = Qpk + ((hd*64 + (c*4+w))*2)*512;
        aq[0] = *(const sh8*)(qb + lane*8);
        aq[1] = *(const sh8*)(qb + 512 + lane*8);
    }
    f32x4 ctx[4], cz[4];
    #pragma unroll
    for (int nb=0;nb<4;nb++){ ctx[nb]=(f32x4){0,0,0,0}; cz[nb]=(f32x4){0,0,0,0}; }
    int t_g = T0 + w*16 + quad*4;
    int rp = tid>>3, e0 = (tid&7)*8, r0 = rp*2;

    sh8 pv0, pv1, pk0, pk1;
    {
        const unsigned short* vrow = vcb + (hd*LK + RQ0)*64;
        const unsigned short* krow = kcb + (hd*LK + RQ0)*64;
        pv0 = *(const sh8*)(vrow + r0*64 + e0);
        pv1 = *(const sh8*)(vrow + (r0+1)*64 + e0);
        pk0 = *(const sh8*)(krow + r0*64 + e0);
        pk1 = *(const sh8*)(krow + (r0+1)*64 + e0);
    }
    for (int sub=0; sub<6; sub++){
        int RB = RQ0 + sub*64;
        __syncthreads();
        {
            float g0 = gl[(RB + r0)/KF - tq0];
            float g1 = gl[(RB + r0 + 1)/KF - tq0];
            *(sh8*)(&Vraw[r0*72 + e0]) = pv0;
            *(sh8*)(&Vraw[(r0+1)*72 + e0]) = pv1;
            #pragma unroll
            for (int j=0;j<8;j++){
                unsigned int pv = (unsigned int)f2bf(bf2f((unsigned short)pv0[j])*g0)
                                | ((unsigned int)f2bf(bf2f((unsigned short)pv1[j])*g1)<<16);
                *(unsigned int*)(&VT[(e0+j)*VTS + r0]) = pv;
                unsigned int pk = (unsigned int)(unsigned short)pk0[j]
                                | ((unsigned int)(unsigned short)pk1[j]<<16);
                *(unsigned int*)(&KT[(e0+j)*VTS + r0]) = pk;
            }
        }
        if (sub < 5){
            const unsigned short* vrow = vcb + (hd*LK + RB + 64)*64;
            const unsigned short* krow = kcb + (hd*LK + RB + 64)*64;
            pv0 = *(const sh8*)(vrow + r0*64 + e0);
            pv1 = *(const sh8*)(vrow + (r0+1)*64 + e0);
            pk0 = *(const sh8*)(krow + r0*64 + e0);
            pk1 = *(const sh8*)(krow + (r0+1)*64 + e0);
        }
        __syncthreads();
        f32x4 S[4];
        #pragma unroll
        for (int nb=0;nb<4;nb++) S[nb]=(f32x4){0,0,0,0};
        #pragma unroll
        for (int ks=0;ks<2;ks++){
            #pragma unroll
            for (int nb=0;nb<4;nb++){
                sh8 b = *(const sh8*)(&Vraw[(nb*16+lm)*72 + ks*32 + quad*8]);
                S[nb] = __builtin_amdgcn_mfma_f32_16x16x32_bf16(aq[ks], b, S[nb], 0,0,0);
            }
        }
        #pragma unroll
        for (int nb=0;nb<4;nb++){
            int row_l = nb*16+lm;
            int tp = (RB + row_l)/KF;
            float g = gl[tp - tq0];
            #pragma unroll
            for (int r=0;r<4;r++){
                float v = (t_g + r >= tp) ? S[nb][r]*g : 0.f;
                As[w][(quad*4+r)*ASS + row_l] = f2bf(v);
            }
        }
        #pragma unroll
        for (int ks=0;ks<2;ks++){
            sh8 a2 = *(const sh8*)(&As[w][lm*ASS + ks*32 + quad*8]);
            sh8 av = ld8_8B(&VT[(w*16+lm)*VTS + ks*32 + quad*8]);
            #pragma unroll
            for (int nb=0;nb<4;nb++){
                sh8 bk = ld8_8B(&KT[(nb*16+lm)*VTS + ks*32 + quad*8]);
                ctx[nb] = __builtin_amdgcn_mfma_f32_16x16x32_bf16(a2, bk, ctx[nb], 0,0,0);
                cz[nb]  = __builtin_amdgcn_mfma_f32_16x16x32_bf16(av, bk, cz[nb], 0,0,0);
            }
        }
    }
    #pragma unroll
    for (int nb=0;nb<4;nb++){
        #pragma unroll
        for (int r=0;r<4;r++){
            atomicAdd(&cpart[(hd*Ll + t_g + r)*64 + nb*16+lm], ctx[nb][r]);
        }
    }
    int ob = ((hd*16+c)*4+qq)*4096;
    #pragma unroll
    for (int nb=0;nb<4;nb++){
        #pragma unroll
        for (int r=0;r<4;r++){
            czp[ob + (w*16+quad*4+r)*64 + nb*16+lm] = f2bf(cz[nb][r]);
        }
    }
}

// exclusive chunk prefix (bf16 in) -> bf16 B-frag layout (coalesced, 32K threads)
__global__ __launch_bounds__(256) void s0_kernel(
    const unsigned short* __restrict__ czp, unsigned short* __restrict__ S0b)
{
    int idx = blockIdx.x*256 + threadIdx.x;   // [d][e] position
    int hd = blockIdx.y;
    int d = idx>>6, e = idx&63;
    int frag = (d>>5)*2048 + (e>>4)*512 + ((((d>>3)&3)*16) + (e&15))*8 + (d&7);
    float a = 0.f;
    for (int c=0;c<16;c++){
        S0b[(hd*16+c)*4096 + frag] = f2bf(a);
        int b = ((hd*16+c)*4)*4096 + idx;
        a += bf2f(czp[b]) + bf2f(czp[b+4096]) + bf2f(czp[b+2*4096]) + bf2f(czp[b+3*4096]);
    }
}

// combine (MFMA): Cpk = factor * ( Qpk @ S0b + cpart )
__global__ __launch_bounds__(256) void combine_kernel(
    const unsigned short* __restrict__ Qpk, const unsigned short* __restrict__ S0b,
    const float* __restrict__ cpart, const float* __restrict__ factor,
    unsigned short* __restrict__ Cpk)
{
    int c=blockIdx.x, hd=blockIdx.y;
    int tid=threadIdx.x, wid=tid>>6, lane=tid&63, quad=lane>>4, lm=lane&15;
    int mb = c*4 + wid;
    sh8 aq0 = *(const sh8*)(Qpk + ((hd*64+mb)*2)*512 + lane*8);
    sh8 aq1 = *(const sh8*)(Qpk + ((hd*64+mb)*2+1)*512 + lane*8);
    const unsigned short* sb = S0b + (hd*16+c)*4096;
    f32x4 acc[4];
    #pragma unroll
    for (int nb=0;nb<4;nb++) acc[nb]=(f32x4){0.f,0.f,0.f,0.f};
    #pragma unroll
    for (int ks=0;ks<2;ks++){
        sh8 a = ks ? aq1 : aq0;
        #pragma unroll
        for (int nb=0;nb<4;nb++){
            sh8 b = *(const sh8*)(sb + ks*2048 + nb*512 + lane*8);
            acc[nb] = __builtin_amdgcn_mfma_f32_16x16x32_bf16(a, b, acc[nb], 0,0,0);
        }
    }
    float fv[4];
    #pragma unroll
    for (int r=0;r<4;r++) fv[r] = factor[hd*Ll + mb*16 + quad*4 + r];
    #pragma unroll
    for (int nb=0;nb<4;nb++){
        int e = nb*16 + lm;
        int dim = hd*64 + e;
        int ks2 = dim>>5, koff = dim&31, qd = koff>>3, jj = koff&7;
        #pragma unroll
        for (int r=0;r<4;r++){
            int t = mb*16 + quad*4 + r;
            float v = acc[nb][r] + cpart[(hd*Ll + t)*64 + e];
            v *= fv[r];
            Cpk[((t>>4)*16 + ks2)*512 + qd*128 + (t&15)*8 + jj] = f2bf(v);
        }
    }
}

// out = Cpk @ Wopk + bo
__global__ __launch_bounds__(256) void outprojm_kernel(
    const unsigned short* __restrict__ Cpk, const unsigned short* __restrict__ Wopk,
    const float* __restrict__ bo, float* __restrict__ out)
{
    int mt=blockIdx.x, nt=blockIdx.y;
    int tid=threadIdx.x, wid=tid>>6, lane=tid&63;
    int mb=mt*4+wid;
    f32x4 acc[4];
    #pragma unroll
    for (int nb=0;nb<4;nb++) acc[nb]=(f32x4){0.f,0.f,0.f,0.f};
    for (int ks=0;ks<16;ks++){
        sh8 a = *(const sh8*)(Cpk + (mb*16+ks)*512 + lane*8);
        #pragma unroll
        for (int nb2=0;nb2<4;nb2++){
            sh8 b = *(const sh8*)(Wopk + ((nt*4+nb2)*16+ks)*512 + lane*8);
            acc[nb2] = __builtin_amdgcn_mfma_f32_16x16x32_bf16(a, b, acc[nb2], 0,0,0);
        }
    }
    int quad=lane>>4, col=lane&15;
    #pragma unroll
    for (int nb2=0;nb2<4;nb2++){
        int n = nt*64 + nb2*16 + col;
        float bval = bo[n];
        #pragma unroll
        for (int r=0;r<4;r++){
            out[(mb*16+quad*4+r)*Dm + n] = acc[nb2][r] + bval;
        }
    }
}

extern "C" void kernel_launch(void* const* d_in, const int* in_sizes, int n_in,
                              void* d_out, int out_size, void* d_ws, size_t ws_size,
                              hipStream_t stream)
{
    (void)in_sizes; (void)n_in; (void)out_size; (void)ws_size;
    const float* x   =(const float*)d_in[0];
    const float* Wq  =(const float*)d_in[1];
    const float* bq  =(const float*)d_in[2];
    const float* Wk  =(const float*)d_in[3];
    const float* bk  =(const float*)d_in[4];
    const float* Wv  =(const float*)d_in[5];
    const float* bv  =(const float*)d_in[6];
    const float* Wo  =(const float*)d_in[7];
    const float* bo  =(const float*)d_in[8];
    const float* Wg  =(const float*)d_in[9];
    const float* bg  =(const float*)d_in[10];
    const float* kvs =(const float*)d_in[11];
    const float* qks =(const float*)d_in[12];
    const float* filt=(const float*)d_in[13];
    float* ws = (float*)d_ws;
    float* simg  = ws+OFF_SIM;
    float* logits= ws+OFF_LOGITS;
    float* gates = ws+OFF_GATES;
    float* factor= ws+OFF_FACTOR;
    float* cpart = ws+OFF_CPART;
    unsigned short* vcb  = (unsigned short*)(ws + OFF_VCB);
    unsigned short* kcb  = (unsigned short*)(ws + OFF_KCB);
    unsigned short* Qpk  = (unsigned short*)(ws + OFF_QPK);
    unsigned short* Mpk  = (unsigned short*)(ws + OFF_MPK);
    unsigned short* Wopk = (unsigned short*)(ws + OFF_WOPK);
    unsigned short* Cpk  = (unsigned short*)(ws + OFF_CPK);
    unsigned short* czp  = (unsigned short*)(ws + OFF_CZP);
    unsigned short* S0b  = (unsigned short*)(ws + OFF_S0);
    unsigned short* Fpk16= (unsigned short*)(ws + OFF_FPK_F);
    unsigned short* Upk  = (unsigned short*)(ws + OFF_UPK_F);
    unsigned short* Apk  = (unsigned short*)(ws + OFF_APK_F);
    unsigned short* Bpk  = (unsigned short*)(ws + OFF_BPK_F);
    float* out   = (float*)d_out;

    pack_all_kernel<<<dim3(361),    256,0,stream>>>(x,Wq,Wk,Wv,Wo,kvs,Wg,filt,
                                                    Apk,Bpk,Wopk,Mpk,Fpk16,logits,cpart);
    qkvn_kernel   <<<dim3(64,8),    64, 0,stream>>>(Apk,Bpk,bq,bk,bv,qks,simg,Upk,Qpk);
    convf_kernel  <<<dim3(8,8,8),   256,0,stream>>>(Fpk16,Upk,Mpk,vcb,kcb,logits);
    scan_kernel   <<<dim3(8),       256,0,stream>>>(simg,logits,bg,gates,factor);
    p3cz_kernel   <<<dim3(16,4,8),  256,0,stream>>>(Qpk,vcb,kcb,gates,cpart,czp);
    s0_kernel     <<<dim3(16,8),    256,0,stream>>>(czp,S0b);
    combine_kernel<<<dim3(16,8),    256,0,stream>>>(Qpk,S0b,cpart,factor,Cpk);
    outprojm_kernel<<<dim3(16,8),   256,0,stream>>>(Cpk,Wopk,bo,out);
}